// Round 5
// baseline (551.969 us; speedup 1.0000x reference)
//
#include <hip/hip_runtime.h>
#include <hip/hip_bf16.h>
#include <hip/hip_fp16.h>

// DeepSetPred: encoder MLP (MFMA fp16) -> segment sum -> predictor MLP (fp32)
// T=131072, E=256, H=512, C=256, O=32, NSEG=128
// R5: 32-token tiles, 256-thread blocks (4 waves), ~39KB LDS -> 4 blocks/CU.
//     Same 16 waves/CU as R4 but 4 independent barrier groups instead of 2:
//     phase-start L2-latency bursts and barrier drains of one block overlap
//     with MFMA of the other three (R4 post-mortem: 65% of time in no-counter
//     wait state = barrier lockstep). MT=8/NT=2 per wave, acc=64 AGPR.

typedef _Float16 half8v __attribute__((ext_vector_type(8)));
typedef _Float16 half4v __attribute__((ext_vector_type(4)));
typedef float f32x4 __attribute__((ext_vector_type(4)));

#define TANH_SCALE 2.8853900817779268f  // 2*log2(e)

// strides with +16B pad: bank-balanced and affine in k
#define W_STR 528    // words row: 256 f16 + 8 pad
#define H_STR 1040   // h row: 512 f16 + 8 pad
#define E_STRF 33    // encT row: 32 f32 + 1 pad (floats)

// ---------------- weight transpose + fp16 cast (+tanh prescale) --------------
__global__ void wt_kernel(const float* __restrict__ W1, const float* __restrict__ W2,
                          const float* __restrict__ W3,
                          _Float16* __restrict__ W1T, _Float16* __restrict__ W2T,
                          _Float16* __restrict__ W3T) {
    int idx = blockIdx.x * 256 + threadIdx.x;
    if (idx < 131072) {                       // W1 [256][512] -> W1T [512][256], scaled
        int n = idx >> 8, k = idx & 255;
        W1T[idx] = (_Float16)(W1[k * 512 + n] * TANH_SCALE);
    } else if (idx < 393216) {                // W2 [512][512] -> W2T [512][512], scaled
        int j = idx - 131072, n = j >> 9, k = j & 511;
        W2T[j] = (_Float16)(W2[k * 512 + n] * TANH_SCALE);
    } else if (idx < 524288) {                // W3 [512][256] -> W3T [256][512]
        int j = idx - 393216, n = j >> 9, k = j & 511;
        W3T[j] = (_Float16)W3[k * 256 + n];
    }
}

// ---------------- encoder ----------------
// D[M=out_feat][N=32 tokens] = WT(MxK) * actT(Kx32); acts in LDS [t][k] fp16.
template<int K, int MT, int STR>
__device__ __forceinline__ void mlp_layer(const _Float16* __restrict__ WT, int mbase,
                                          const char* lds_in, const float* sbias_layer,
                                          int lane, f32x4 acc[MT][2]) {
    const int kgrp = 8 * (lane >> 4);
    const int r = lane & 15;
    const int fr0 = (lane >> 4) * 4;
    #pragma unroll
    for (int mt = 0; mt < MT; ++mt) {
        f32x4 bv = *(const f32x4*)(sbias_layer + mbase + mt * 16 + fr0);
        #pragma unroll
        for (int nt = 0; nt < 2; ++nt) acc[mt][nt] = bv;
    }
    const char* bbase = lds_in + r * STR + kgrp * 2;
    const _Float16* arow = WT + (size_t)(mbase + r) * K + kgrp;
    #pragma unroll
    for (int kk = 0; kk < K / 32; ++kk) {
        half8v a[MT];
        #pragma unroll
        for (int mt = 0; mt < MT; ++mt)
            a[mt] = *(const half8v*)(arow + (size_t)mt * 16 * K + kk * 32);
        #pragma unroll
        for (int nt = 0; nt < 2; ++nt) {
            half8v b = *(const half8v*)(bbase + nt * 16 * STR + kk * 64);
            #pragma unroll
            for (int mt = 0; mt < MT; ++mt)
                acc[mt][nt] = __builtin_amdgcn_mfma_f32_16x16x32_f16(
                    a[mt], b, acc[mt][nt], 0, 0, 0);
        }
    }
}

// acc (bias included, pre-scaled by 2*log2e) -> tanh -> fp16 LDS [t][f]
template<int MT>
__device__ __forceinline__ void store_h(char* lds_out, const f32x4 acc[MT][2],
                                        int mbase, int lane) {
    const int r = lane & 15;
    const int fr0 = (lane >> 4) * 4;
    #pragma unroll
    for (int mt = 0; mt < MT; ++mt) {
        int f0 = mbase + mt * 16 + fr0;
        #pragma unroll
        for (int nt = 0; nt < 2; ++nt) {
            int t = nt * 16 + r;
            half4v hv;
            #pragma unroll
            for (int reg = 0; reg < 4; ++reg) {
                float e = __builtin_amdgcn_exp2f(acc[mt][nt][reg]);   // 2^(s*z)
                float rr = __builtin_amdgcn_rcpf(e + 1.0f);
                hv[reg] = (_Float16)fmaf(-2.0f, rr, 1.0f);            // tanh(z)
            }
            *(half4v*)(lds_out + t * H_STR + f0 * 2) = hv;
        }
    }
}

__global__ __launch_bounds__(256, 4) void encoder_kernel(
    const float* __restrict__ words, const int* __restrict__ seg_ids,
    const _Float16* __restrict__ W1T, const _Float16* __restrict__ W2T,
    const _Float16* __restrict__ W3T,
    const float* __restrict__ b1, const float* __restrict__ b2,
    const float* __restrict__ b3, float* __restrict__ enc) {
    __shared__ __align__(16) char buf[33792];   // words 32x528 / h 32x1040 / encT 256x33x4
    __shared__ __align__(16) float sbias[1280]; // s*b1(512) s*b2(512) b3(256)
    __shared__ int sseg[32];

    const int tid = threadIdx.x;
    const int lane = tid & 63;
    const int wave = tid >> 6;
    const int tok0 = blockIdx.x * 32;

    sbias[tid] = b1[tid] * TANH_SCALE;
    sbias[tid + 256] = b1[tid + 256] * TANH_SCALE;
    sbias[tid + 512] = b2[tid] * TANH_SCALE;
    sbias[tid + 768] = b2[tid + 256] * TANH_SCALE;
    sbias[tid + 1024] = b3[tid];
    if (tid < 32) sseg[tid] = seg_ids[tok0 + tid];

    // stage words tile -> fp16 LDS [t][k], row stride 528B
    const float* wsrc = words + (size_t)tok0 * 256;
    #pragma unroll
    for (int it = 0; it < 8; ++it) {
        int i = it * 256 + tid;            // float4 index, 2048 total
        float4 v = ((const float4*)wsrc)[i];
        int t = i >> 6;
        int col = i & 63;                  // 8B half4 slot within row
        half4v hv = { (_Float16)v.x, (_Float16)v.y, (_Float16)v.z, (_Float16)v.w };
        *(half4v*)(buf + t * W_STR + col * 8) = hv;
    }
    __syncthreads();

    // layer 1: words[32][256] -> h1[32][512] (in place)
    {
        f32x4 acc[8][2];
        mlp_layer<256, 8, W_STR>(W1T, wave * 128, buf, sbias, lane, acc);
        __syncthreads();
        store_h<8>(buf, acc, wave * 128, lane);
    }
    __syncthreads();

    // layer 2: h1 -> h2 (in place)
    {
        f32x4 acc[8][2];
        mlp_layer<512, 8, H_STR>(W2T, wave * 128, buf, sbias + 512, lane, acc);
        __syncthreads();
        store_h<8>(buf, acc, wave * 128, lane);
    }
    __syncthreads();

    // layer 3: h2 -> encT [256][33] f32 (in place; bias in acc, no tanh)
    {
        f32x4 acc[4][2];
        mlp_layer<512, 4, H_STR>(W3T, wave * 64, buf, sbias + 1024, lane, acc);
        __syncthreads();
        float* encT = (float*)buf;
        const int r = lane & 15;
        const int fr0 = (lane >> 4) * 4;
        #pragma unroll
        for (int mt = 0; mt < 4; ++mt) {
            int f0 = wave * 64 + mt * 16 + fr0;
            #pragma unroll
            for (int nt = 0; nt < 2; ++nt) {
                int t = nt * 16 + r;
                #pragma unroll
                for (int reg = 0; reg < 4; ++reg)
                    encT[(f0 + reg) * E_STRF + t] = acc[mt][nt][reg];
            }
        }
    }
    __syncthreads();

    // segment reduction: sorted seg_ids -> running sum, atomic on boundary
    {
        int f = tid;                       // 256 threads = 256 features
        const float* encT = (const float*)buf;
        float a = 0.0f;
        int cur = sseg[0];
        for (int t = 0; t < 32; ++t) {
            float v = encT[f * E_STRF + t];
            int s = sseg[t];
            if (s != cur) { atomicAdd(&enc[cur * 256 + f], a); a = 0.0f; cur = s; }
            a += v;
        }
        atomicAdd(&enc[cur * 256 + f], a);
    }
}

// ---------------- predictor (tiny, fp32) ----------------
__global__ __launch_bounds__(256) void pred_kernel(
    const float* __restrict__ enc,
    const float* __restrict__ P1, const float* __restrict__ pb1,
    const float* __restrict__ P2, const float* __restrict__ pb2,
    const float* __restrict__ P3, const float* __restrict__ pb3,
    float* __restrict__ out) {
    __shared__ float se[256];
    __shared__ float sp[512];
    __shared__ float red[256];
    const int tid = threadIdx.x, b = blockIdx.x;
    se[tid] = enc[b * 256 + tid];
    __syncthreads();
    float a0 = pb1[tid], a1 = pb1[tid + 256];
    for (int k = 0; k < 256; ++k) {
        float e = se[k];
        a0 = fmaf(e, P1[k * 512 + tid], a0);
        a1 = fmaf(e, P1[k * 512 + tid + 256], a1);
    }
    sp[tid] = tanhf(a0);
    sp[tid + 256] = tanhf(a1);
    __syncthreads();
    a0 = pb2[tid]; a1 = pb2[tid + 256];
    for (int k = 0; k < 512; ++k) {
        float p = sp[k];
        a0 = fmaf(p, P2[k * 512 + tid], a0);
        a1 = fmaf(p, P2[k * 512 + tid + 256], a1);
    }
    __syncthreads();
    sp[tid] = tanhf(a0);
    sp[tid + 256] = tanhf(a1);
    __syncthreads();
    int j = tid & 31, part = tid >> 5;
    float s = 0.0f;
    for (int k = part * 64; k < part * 64 + 64; ++k)
        s = fmaf(sp[k], P3[k * 32 + j], s);
    red[tid] = s;
    __syncthreads();
    if (tid < 128) red[tid] += red[tid + 128];
    __syncthreads();
    if (tid < 64) red[tid] += red[tid + 64];
    __syncthreads();
    if (tid < 32) out[b * 32 + tid] = red[tid] + red[tid + 32] + pb3[tid];
}

extern "C" void kernel_launch(void* const* d_in, const int* in_sizes, int n_in,
                              void* d_out, int out_size, void* d_ws, size_t ws_size,
                              hipStream_t stream) {
    const float* words = (const float*)d_in[0];
    const int* seg_ids = (const int*)d_in[1];
    const float* W1 = (const float*)d_in[2];
    const float* b1 = (const float*)d_in[3];
    const float* W2 = (const float*)d_in[4];
    const float* b2 = (const float*)d_in[5];
    const float* W3 = (const float*)d_in[6];
    const float* b3 = (const float*)d_in[7];
    const float* P1 = (const float*)d_in[8];
    const float* pb1 = (const float*)d_in[9];
    const float* P2 = (const float*)d_in[10];
    const float* pb2 = (const float*)d_in[11];
    const float* P3 = (const float*)d_in[12];
    const float* pb3 = (const float*)d_in[13];
    float* out = (float*)d_out;

    char* ws = (char*)d_ws;
    _Float16* W1T = (_Float16*)(ws);            // 512*256*2 = 256KB
    _Float16* W2T = (_Float16*)(ws + 262144);   // 512*512*2 = 512KB
    _Float16* W3T = (_Float16*)(ws + 786432);   // 256*512*2 = 256KB
    float* enc = (float*)(ws + 1048576);        // 128*256*4 = 128KB

    hipMemsetAsync(enc, 0, 128 * 256 * 4, stream);
    wt_kernel<<<524288 / 256, 256, 0, stream>>>(W1, W2, W3, W1T, W2T, W3T);
    encoder_kernel<<<4096, 256, 0, stream>>>(words, seg_ids, W1T, W2T, W3T,
                                             b1, b2, b3, enc);
    pred_kernel<<<128, 256, 0, stream>>>(enc, P1, pb1, P2, pb2, P3, pb3, out);
}

// Round 6
// 304.324 us; speedup vs baseline: 1.8138x; 1.8138x over previous
//
#include <hip/hip_runtime.h>
#include <hip/hip_bf16.h>
#include <hip/hip_fp16.h>

// DeepSetPred: encoder MLP (MFMA fp16) -> segment sum -> predictor MLP (fp32)
// T=131072, E=256, H=512, C=256, O=32, NSEG=128
// R6: back to R4 geometry (64-token tile, 8 waves, in-place LDS, 2 blocks/CU).
//     Per-wave tiling MT=2/NT=4 in TWO feature passes (acc 32+32 AGPR) so a
//     full depth-1 double buffer of A (global/L2) AND B (LDS) fits in the
//     64-arch-VGPR budget: a0[2]+a1[2]+b0[4]+b1[4] = 48 regs. R4's MT=4
//     prefetch needed 32 more regs than existed -> silent spill (WRITE_SIZE
//     18MB) and no pipelining (MfmaUtil stuck at 20%).

typedef _Float16 half8v __attribute__((ext_vector_type(8)));
typedef _Float16 half4v __attribute__((ext_vector_type(4)));
typedef float f32x4 __attribute__((ext_vector_type(4)));

#define TANH_SCALE 2.8853900817779268f  // 2*log2(e)

// strides (bytes) with +16B pad: bank-balanced and affine in k
#define W_STR 528    // words row: 256 f16 + 8 pad
#define H_STR 1040   // h row: 512 f16 + 8 pad
#define E_STRF 65    // encT row: 64 f32 + 1 pad (floats)

// ---------------- weight transpose + fp16 cast (+tanh prescale) --------------
__global__ void wt_kernel(const float* __restrict__ W1, const float* __restrict__ W2,
                          const float* __restrict__ W3,
                          _Float16* __restrict__ W1T, _Float16* __restrict__ W2T,
                          _Float16* __restrict__ W3T) {
    int idx = blockIdx.x * 256 + threadIdx.x;
    if (idx < 131072) {                       // W1 [256][512] -> W1T [512][256], scaled
        int n = idx >> 8, k = idx & 255;
        W1T[idx] = (_Float16)(W1[k * 512 + n] * TANH_SCALE);
    } else if (idx < 393216) {                // W2 [512][512] -> W2T [512][512], scaled
        int j = idx - 131072, n = j >> 9, k = j & 511;
        W2T[j] = (_Float16)(W2[k * 512 + n] * TANH_SCALE);
    } else if (idx < 524288) {                // W3 [512][256] -> W3T [256][512]
        int j = idx - 393216, n = j >> 9, k = j & 511;
        W3T[j] = (_Float16)W3[k * 256 + n];
    }
}

// ---------------- encoder ----------------
// One pass: D[32 feats x 64 tokens] = WT-slice * actT, K-loop double-buffered.
// acc[2][4], A = 2 fragments (8 VGPR/set), B = 4 fragments (16 VGPR/set).
template<int K, int STR>
__device__ __forceinline__ void mlp_pass(const _Float16* __restrict__ WT, int mbase,
                                         const char* lds_in, const float* sbias_layer,
                                         int lane, f32x4 acc[2][4]) {
    const int kgrp = 8 * (lane >> 4);
    const int r = lane & 15;
    const int fr0 = (lane >> 4) * 4;
    #pragma unroll
    for (int mt = 0; mt < 2; ++mt) {
        f32x4 bv = *(const f32x4*)(sbias_layer + mbase + mt * 16 + fr0);
        #pragma unroll
        for (int nt = 0; nt < 4; ++nt) acc[mt][nt] = bv;
    }
    const char* bbase = lds_in + r * STR + kgrp * 2;
    const _Float16* arow = WT + (size_t)(mbase + r) * K + kgrp;

    half8v a0[2], a1[2], b0[4], b1[4];
    #pragma unroll
    for (int mt = 0; mt < 2; ++mt)
        a0[mt] = *(const half8v*)(arow + (size_t)mt * 16 * K);
    #pragma unroll
    for (int nt = 0; nt < 4; ++nt)
        b0[nt] = *(const half8v*)(bbase + nt * 16 * STR);

    #pragma unroll
    for (int kk = 0; kk < K / 32; kk += 2) {
        // prefetch kk+1 (always exists: K/32 even)
        #pragma unroll
        for (int mt = 0; mt < 2; ++mt)
            a1[mt] = *(const half8v*)(arow + (size_t)mt * 16 * K + (kk + 1) * 32);
        #pragma unroll
        for (int nt = 0; nt < 4; ++nt)
            b1[nt] = *(const half8v*)(bbase + nt * 16 * STR + (kk + 1) * 64);
        // compute kk
        #pragma unroll
        for (int nt = 0; nt < 4; ++nt)
            #pragma unroll
            for (int mt = 0; mt < 2; ++mt)
                acc[mt][nt] = __builtin_amdgcn_mfma_f32_16x16x32_f16(
                    a0[mt], b0[nt], acc[mt][nt], 0, 0, 0);
        // prefetch kk+2
        if (kk + 2 < K / 32) {
            #pragma unroll
            for (int mt = 0; mt < 2; ++mt)
                a0[mt] = *(const half8v*)(arow + (size_t)mt * 16 * K + (kk + 2) * 32);
            #pragma unroll
            for (int nt = 0; nt < 4; ++nt)
                b0[nt] = *(const half8v*)(bbase + nt * 16 * STR + (kk + 2) * 64);
        }
        // compute kk+1
        #pragma unroll
        for (int nt = 0; nt < 4; ++nt)
            #pragma unroll
            for (int mt = 0; mt < 2; ++mt)
                acc[mt][nt] = __builtin_amdgcn_mfma_f32_16x16x32_f16(
                    a1[mt], b1[nt], acc[mt][nt], 0, 0, 0);
    }
}

// acc (bias included, pre-scaled by 2*log2e) -> tanh -> fp16 LDS [t][f]
__device__ __forceinline__ void store_h2(char* lds_out, const f32x4 acc[2][4],
                                         int mbase, int lane) {
    const int r = lane & 15;
    const int fr0 = (lane >> 4) * 4;
    #pragma unroll
    for (int mt = 0; mt < 2; ++mt) {
        int f0 = mbase + mt * 16 + fr0;
        #pragma unroll
        for (int nt = 0; nt < 4; ++nt) {
            int t = nt * 16 + r;
            half4v hv;
            #pragma unroll
            for (int reg = 0; reg < 4; ++reg) {
                float e = __builtin_amdgcn_exp2f(acc[mt][nt][reg]);   // 2^(s*z)
                float rr = __builtin_amdgcn_rcpf(e + 1.0f);
                hv[reg] = (_Float16)fmaf(-2.0f, rr, 1.0f);            // tanh(z)
            }
            *(half4v*)(lds_out + t * H_STR + f0 * 2) = hv;
        }
    }
}

__global__ __launch_bounds__(512, 4) void encoder_kernel(
    const float* __restrict__ words, const int* __restrict__ seg_ids,
    const _Float16* __restrict__ W1T, const _Float16* __restrict__ W2T,
    const _Float16* __restrict__ W3T,
    const float* __restrict__ b1, const float* __restrict__ b2,
    const float* __restrict__ b3, float* __restrict__ enc) {
    __shared__ __align__(16) char buf[66560]; // words 64x528 / h 64x1040 / encT 256x65x4
    __shared__ __align__(16) float sbias[1280]; // s*b1(512) s*b2(512) b3(256)
    __shared__ int sseg[64];

    const int tid = threadIdx.x;
    const int lane = tid & 63;
    const int wave = tid >> 6;
    const int tok0 = blockIdx.x * 64;

    sbias[tid] = b1[tid] * TANH_SCALE;
    sbias[512 + tid] = b2[tid] * TANH_SCALE;
    if (tid < 256) sbias[1024 + tid] = b3[tid];
    if (tid < 64) sseg[tid] = seg_ids[tok0 + tid];

    // stage words tile -> fp16 LDS [t][k], row stride 528B
    const float* wsrc = words + (size_t)tok0 * 256;
    #pragma unroll
    for (int it = 0; it < 8; ++it) {
        int i = it * 512 + tid;            // float4 index, 4096 total
        float4 v = ((const float4*)wsrc)[i];
        int t = i >> 6;
        int col = i & 63;                  // 8B half4 slot within row
        half4v hv = { (_Float16)v.x, (_Float16)v.y, (_Float16)v.z, (_Float16)v.w };
        *(half4v*)(buf + t * W_STR + col * 8) = hv;
    }
    __syncthreads();

    // layer 1: words[64][256] -> h1[64][512], two 256-feature passes, in place
    {
        f32x4 accA[2][4], accB[2][4];
        mlp_pass<256, W_STR>(W1T, wave * 32, buf, sbias, lane, accA);
        mlp_pass<256, W_STR>(W1T, wave * 32 + 256, buf, sbias, lane, accB);
        __syncthreads();
        store_h2(buf, accA, wave * 32, lane);
        store_h2(buf, accB, wave * 32 + 256, lane);
    }
    __syncthreads();

    // layer 2: h1 -> h2, two passes, in place
    {
        f32x4 accA[2][4], accB[2][4];
        mlp_pass<512, H_STR>(W2T, wave * 32, buf, sbias + 512, lane, accA);
        mlp_pass<512, H_STR>(W2T, wave * 32 + 256, buf, sbias + 512, lane, accB);
        __syncthreads();
        store_h2(buf, accA, wave * 32, lane);
        store_h2(buf, accB, wave * 32 + 256, lane);
    }
    __syncthreads();

    // layer 3: h2 -> encT [256][65] f32, one pass (8 waves x 32 = 256 feats)
    {
        f32x4 acc[2][4];
        mlp_pass<512, H_STR>(W3T, wave * 32, buf, sbias + 1024, lane, acc);
        __syncthreads();
        float* encT = (float*)buf;
        const int r = lane & 15;
        const int fr0 = (lane >> 4) * 4;
        #pragma unroll
        for (int mt = 0; mt < 2; ++mt) {
            int f0 = wave * 32 + mt * 16 + fr0;
            #pragma unroll
            for (int nt = 0; nt < 4; ++nt) {
                int t = nt * 16 + r;
                #pragma unroll
                for (int reg = 0; reg < 4; ++reg)
                    encT[(f0 + reg) * E_STRF + t] = acc[mt][nt][reg];
            }
        }
    }
    __syncthreads();

    // segment reduction: sorted seg_ids -> running sum, atomic on boundary
    {
        int f = tid & 255;
        int hh = tid >> 8;
        int t0 = hh * 32;
        const float* encT = (const float*)buf;
        float a = 0.0f;
        int cur = sseg[t0];
        for (int i = 0; i < 32; ++i) {
            int t = t0 + i;
            float v = encT[f * E_STRF + t];
            int s = sseg[t];
            if (s != cur) { atomicAdd(&enc[cur * 256 + f], a); a = 0.0f; cur = s; }
            a += v;
        }
        atomicAdd(&enc[cur * 256 + f], a);
    }
}

// ---------------- predictor (tiny, fp32) ----------------
__global__ __launch_bounds__(256) void pred_kernel(
    const float* __restrict__ enc,
    const float* __restrict__ P1, const float* __restrict__ pb1,
    const float* __restrict__ P2, const float* __restrict__ pb2,
    const float* __restrict__ P3, const float* __restrict__ pb3,
    float* __restrict__ out) {
    __shared__ float se[256];
    __shared__ float sp[512];
    __shared__ float red[256];
    const int tid = threadIdx.x, b = blockIdx.x;
    se[tid] = enc[b * 256 + tid];
    __syncthreads();
    float a0 = pb1[tid], a1 = pb1[tid + 256];
    for (int k = 0; k < 256; ++k) {
        float e = se[k];
        a0 = fmaf(e, P1[k * 512 + tid], a0);
        a1 = fmaf(e, P1[k * 512 + tid + 256], a1);
    }
    sp[tid] = tanhf(a0);
    sp[tid + 256] = tanhf(a1);
    __syncthreads();
    a0 = pb2[tid]; a1 = pb2[tid + 256];
    for (int k = 0; k < 512; ++k) {
        float p = sp[k];
        a0 = fmaf(p, P2[k * 512 + tid], a0);
        a1 = fmaf(p, P2[k * 512 + tid + 256], a1);
    }
    __syncthreads();
    sp[tid] = tanhf(a0);
    sp[tid + 256] = tanhf(a1);
    __syncthreads();
    int j = tid & 31, part = tid >> 5;
    float s = 0.0f;
    for (int k = part * 64; k < part * 64 + 64; ++k)
        s = fmaf(sp[k], P3[k * 32 + j], s);
    red[tid] = s;
    __syncthreads();
    if (tid < 128) red[tid] += red[tid + 128];
    __syncthreads();
    if (tid < 64) red[tid] += red[tid + 64];
    __syncthreads();
    if (tid < 32) out[b * 32 + tid] = red[tid] + red[tid + 32] + pb3[tid];
}

extern "C" void kernel_launch(void* const* d_in, const int* in_sizes, int n_in,
                              void* d_out, int out_size, void* d_ws, size_t ws_size,
                              hipStream_t stream) {
    const float* words = (const float*)d_in[0];
    const int* seg_ids = (const int*)d_in[1];
    const float* W1 = (const float*)d_in[2];
    const float* b1 = (const float*)d_in[3];
    const float* W2 = (const float*)d_in[4];
    const float* b2 = (const float*)d_in[5];
    const float* W3 = (const float*)d_in[6];
    const float* b3 = (const float*)d_in[7];
    const float* P1 = (const float*)d_in[8];
    const float* pb1 = (const float*)d_in[9];
    const float* P2 = (const float*)d_in[10];
    const float* pb2 = (const float*)d_in[11];
    const float* P3 = (const float*)d_in[12];
    const float* pb3 = (const float*)d_in[13];
    float* out = (float*)d_out;

    char* ws = (char*)d_ws;
    _Float16* W1T = (_Float16*)(ws);            // 512*256*2 = 256KB
    _Float16* W2T = (_Float16*)(ws + 262144);   // 512*512*2 = 512KB
    _Float16* W3T = (_Float16*)(ws + 786432);   // 256*512*2 = 256KB
    float* enc = (float*)(ws + 1048576);        // 128*256*4 = 128KB

    hipMemsetAsync(enc, 0, 128 * 256 * 4, stream);
    wt_kernel<<<524288 / 256, 256, 0, stream>>>(W1, W2, W3, W1T, W2T, W3T);
    encoder_kernel<<<2048, 512, 0, stream>>>(words, seg_ids, W1T, W2T, W3T,
                                             b1, b2, b3, enc);
    pred_kernel<<<128, 256, 0, stream>>>(enc, P1, pb1, P2, pb2, P3, pb3, out);
}